// Round 3
// baseline (718.362 us; speedup 1.0000x reference)
//
#include <hip/hip_runtime.h>
#include <stdint.h>

#define B_ 1024
#define Q_ 65536
#define D_ 512
#define MT 128
#define NT 128
#define BK 64
#define NSPLIT 128
#define NCHUNK (Q_ / NSPLIT)   // 512
#define NTILES (NCHUNK / NT)   // 4
#define KITERS (D_ / BK)       // 8

// ---- workspace layout (bytes) ----
// [0,16)     : ce_acc f32 | neg_acc f32 | npos i32 | nneg i32
// [WS_LSE)   : LSE partials float2(M,Z), idx ((l*B+row)*128+split)    (2 MB)
// [WS_TOPK)  : top-10 partials, idx ((l*B+row)*128+split)*10          (10.5 MB)
// [13 MB)    : p bf16 (1 MB)
// [14 MB)    : queue[0] bf16 (64 MB)
// [78 MB)    : w = m*q1+(1-m)*q0 bf16 (64 MB)   -> total 142 MB
#define WS_ACC  0
#define WS_LSE  1024
#define WS_TOPK (WS_LSE + 2 * B_ * NSPLIT * 2 * 4)
#define WS_PBF  (13u * 1024u * 1024u)
#define WS_QBF0 (14u * 1024u * 1024u)
#define WS_WBF  (78u * 1024u * 1024u)

// ---- LDS layout (aliased, barrier-separated) ----
// staging: sA[0,16K) sB[16K,32K), 128 rows x 128 B, 16B-XOR swizzle
// epilogue: bf16 tile 128 x 264 B = 33792 B, aliases staging
// topk spill: floats [0, 5120)
#define SA_OFF 0
#define SB_OFF 16384
#define EPI_STRIDE 264
#define SMEM_BYTES 33792

typedef __attribute__((ext_vector_type(8))) short short8;
typedef __attribute__((ext_vector_type(4))) short short4v;
typedef __attribute__((ext_vector_type(4))) float f32x4;

__device__ __forceinline__ unsigned short f2bf(float x) {
  union { float f; uint32_t u; } v; v.f = x;
  uint32_t r = v.u + 0x7fffu + ((v.u >> 16) & 1u);   // RNE
  return (unsigned short)(r >> 16);
}

__device__ __forceinline__ float bf2f(short u) {
  union { uint32_t i; float f; } v;
  v.i = ((uint32_t)(unsigned short)u) << 16;
  return v.f;
}

__device__ __forceinline__ void async16(void* lds, const void* g) {
  void* gg = (void*)g;
  __builtin_amdgcn_global_load_lds(
      (__attribute__((address_space(1))) unsigned int*)gg,
      (__attribute__((address_space(3))) unsigned int*)lds,
      16, 0, 0);
}

// two-pass online logsumexp over one 128-col bf16 row (logits = cos*32)
__device__ __forceinline__ void lse_bf_row(const unsigned char* rowp,
                                           float& M, float& Z) {
  float tmax = -1e30f;
#pragma unroll
  for (int c = 0; c < 32; ++c) {
    short4v v = *(const short4v*)(rowp + c * 8);
    tmax = fmaxf(tmax, fmaxf(fmaxf(bf2f(v.x), bf2f(v.y)),
                             fmaxf(bf2f(v.z), bf2f(v.w))));
  }
  float Mn = fmaxf(M, tmax * 32.0f);
  float fac = __expf(M - Mn);
  float s = 0.0f;
#pragma unroll
  for (int c = 0; c < 32; ++c) {
    short4v v = *(const short4v*)(rowp + c * 8);
    s += __expf(fmaf(bf2f(v.x), 32.0f, -Mn));
    s += __expf(fmaf(bf2f(v.y), 32.0f, -Mn));
    s += __expf(fmaf(bf2f(v.z), 32.0f, -Mn));
    s += __expf(fmaf(bf2f(v.w), 32.0f, -Mn));
  }
  Z = fmaf(Z, fac, s);
  M = Mn;
}

__device__ __forceinline__ void tkins(float v,
    float& t0, float& t1, float& t2, float& t3, float& t4,
    float& t5, float& t6, float& t7, float& t8, float& t9) {
  if (v > t9) {
    t9 = (v > t8) ? t8 : v;
    t8 = (v > t8) ? ((v > t7) ? t7 : v) : t8;
    t7 = (v > t7) ? ((v > t6) ? t6 : v) : t7;
    t6 = (v > t6) ? ((v > t5) ? t5 : v) : t6;
    t5 = (v > t5) ? ((v > t4) ? t4 : v) : t5;
    t4 = (v > t4) ? ((v > t3) ? t3 : v) : t4;
    t3 = (v > t3) ? ((v > t2) ? t2 : v) : t3;
    t2 = (v > t2) ? ((v > t1) ? t1 : v) : t2;
    t1 = (v > t1) ? ((v > t0) ? t0 : v) : t1;
    t0 = (v > t0) ? v : t0;
  }
}

#define TK10(v) tkins((v), rs[0], rs[1], rs[2], rs[3], rs[4], rs[5], rs[6], rs[7], rs[8], rs[9])

// queue fp32 -> {qbf0, wbf} bf16; skips q1 read where mask==0 (90% of rows)
__global__ void cvt_queue_kernel(const float* __restrict__ q,
                                 const float* __restrict__ mask,
                                 unsigned short* __restrict__ qbf0,
                                 unsigned short* __restrict__ wbf) {
  const int row = blockIdx.x * 4 + (threadIdx.x >> 6);
  const int lane = threadIdx.x & 63;
  const float* q0r = q + (size_t)row * D_ + lane * 8;
  float4 a = ((const float4*)q0r)[0];
  float4 b = ((const float4*)q0r)[1];
  short8 o;
  o[0] = (short)f2bf(a.x); o[1] = (short)f2bf(a.y);
  o[2] = (short)f2bf(a.z); o[3] = (short)f2bf(a.w);
  o[4] = (short)f2bf(b.x); o[5] = (short)f2bf(b.y);
  o[6] = (short)f2bf(b.z); o[7] = (short)f2bf(b.w);
  *(short8*)(qbf0 + (size_t)row * D_ + lane * 8) = o;
  float m = mask[row];
  if (m != 0.0f) {        // wave-uniform branch
    const float* q1r = q0r + (size_t)Q_ * D_;
    float4 c = ((const float4*)q1r)[0];
    float4 d = ((const float4*)q1r)[1];
    a.x = fmaf(m, c.x - a.x, a.x); a.y = fmaf(m, c.y - a.y, a.y);
    a.z = fmaf(m, c.z - a.z, a.z); a.w = fmaf(m, c.w - a.w, a.w);
    b.x = fmaf(m, d.x - b.x, b.x); b.y = fmaf(m, d.y - b.y, b.y);
    b.z = fmaf(m, d.z - b.z, b.z); b.w = fmaf(m, d.w - b.w, b.w);
    o[0] = (short)f2bf(a.x); o[1] = (short)f2bf(a.y);
    o[2] = (short)f2bf(a.z); o[3] = (short)f2bf(a.w);
    o[4] = (short)f2bf(b.x); o[5] = (short)f2bf(b.y);
    o[6] = (short)f2bf(b.z); o[7] = (short)f2bf(b.w);
  }
  *(short8*)(wbf + (size_t)row * D_ + lane * 8) = o;
}

__global__ void cvt_bf16_kernel(const float* __restrict__ src,
                                unsigned short* __restrict__ dst, int n8) {
  int i = blockIdx.x * blockDim.x + threadIdx.x;
  int stride = gridDim.x * blockDim.x;
  for (; i < n8; i += stride) {
    const float4* s = (const float4*)src + (size_t)2 * i;
    float4 a = s[0], b = s[1];
    short8 o;
    o[0] = (short)f2bf(a.x); o[1] = (short)f2bf(a.y);
    o[2] = (short)f2bf(a.z); o[3] = (short)f2bf(a.w);
    o[4] = (short)f2bf(b.x); o[5] = (short)f2bf(b.y);
    o[6] = (short)f2bf(b.z); o[7] = (short)f2bf(b.w);
    *(short8*)(dst + (size_t)i * 8) = o;
  }
}

// grid (NSPLIT, 16): x=split -> XCD = split%8 (chunk-sharing blocks co-locate
// on one XCD's L2). y: mblk = y>>1, which = y&1 (0: q0 matrix, 1: w matrix).
__global__ __launch_bounds__(256, 3) void fused_gemm_partial(
    const unsigned short* __restrict__ pbf,
    const unsigned short* __restrict__ qbf0,
    const unsigned short* __restrict__ wbf,
    const int* __restrict__ label,
    char* __restrict__ ws) {
  __shared__ __align__(16) unsigned char smem[SMEM_BYTES];
  __shared__ int olist[MT];
  __shared__ int sh_ocount;
  float* tlbuf = (float*)smem;

  const int tid = threadIdx.x;
  const int split = blockIdx.x;          // 0..127
  const int mblk = blockIdx.y >> 1;      // 0..7
  const int which = blockIdx.y & 1;      // 0 or 1
  const unsigned short* bsrc = which ? wbf : qbf0;
  const int lane = tid & 63;
  const int wv = tid >> 6;
  const int wr = wv >> 1;
  const int wc = wv & 1;
  const int lr = lane & 15;
  const int lg = lane >> 4;

  if (tid == 0) sh_ocount = 0;
  __syncthreads();
  if (tid < MT) {
    if (label[mblk * MT + tid] == -1) {
      int k = atomicAdd(&sh_ocount, 1);
      olist[k] = tid;
    }
  }
  __syncthreads();
  const int noc = sh_ocount;
  int rowloc = -1;
  int sub = 0;
  if (tid >= 128) {
    int task = (tid - 128) >> 2;
    sub = (tid - 128) & 3;
    if (task < noc) rowloc = olist[task];
  }

  // staging lane constants: lane covers row slot*8+(lane>>3),
  // swizzled col16 = (lane&7) ^ (row&7)
  const int srow = lane >> 3;
  const int sc16 = (lane & 7) ^ srow;
  const size_t g_lane_off = (size_t)srow * D_ + sc16 * 8;

  // tid<128: rs[0]=M, rs[1]=Z.  tid>=128: rs[0..9] top-10 list.
  float rs[10];
#pragma unroll
  for (int i = 0; i < 10; ++i) rs[i] = -1e30f;
  if (tid < MT) rs[1] = 0.0f;

  for (int nt = 0; nt < NTILES; ++nt) {
    const int nbase = split * NCHUNK + nt * NT;

    f32x4 acc[4][4];
#pragma unroll
    for (int i = 0; i < 4; ++i)
#pragma unroll
      for (int j = 0; j < 4; ++j) {
        f32x4 z = {0.0f, 0.0f, 0.0f, 0.0f};
        acc[i][j] = z;
      }

    for (int kk = 0; kk < KITERS; ++kk) {
      const size_t kcol = (size_t)kk * BK;
#pragma unroll
      for (int t = 0; t < 4; ++t) {
        const int slot = wv * 4 + t;
        const size_t rbase = (size_t)slot * 8;
        async16(smem + SA_OFF + slot * 1024,
                pbf + ((size_t)mblk * MT + rbase) * D_ + kcol + g_lane_off);
        async16(smem + SB_OFF + slot * 1024,
                bsrc + ((size_t)nbase + rbase) * D_ + kcol + g_lane_off);
      }
      __syncthreads();

#pragma unroll
      for (int s = 0; s < 2; ++s) {
        const int xs = ((s * 4 + lg) ^ (lr & 7)) * 16;
        short8 af[4], bf[4];
#pragma unroll
        for (int i = 0; i < 4; ++i)
          af[i] = *(const short8*)(smem + SA_OFF + (wr * 64 + i * 16 + lr) * 128 + xs);
#pragma unroll
        for (int j = 0; j < 4; ++j)
          bf[j] = *(const short8*)(smem + SB_OFF + (wc * 64 + j * 16 + lr) * 128 + xs);
#pragma unroll
        for (int i = 0; i < 4; ++i)
#pragma unroll
          for (int j = 0; j < 4; ++j)
            acc[i][j] = __builtin_amdgcn_mfma_f32_16x16x32_bf16(af[i], bf[j], acc[i][j], 0, 0, 0);
      }
      __syncthreads();
    }

    // ---- epilogue: bf16 tile, then scans ----
#pragma unroll
    for (int i = 0; i < 4; ++i)
#pragma unroll
      for (int j = 0; j < 4; ++j)
#pragma unroll
        for (int k = 0; k < 4; ++k) {
          const int r = wr * 64 + i * 16 + lg * 4 + k;
          const int c = wc * 64 + j * 16 + lr;
          *(unsigned short*)(smem + r * EPI_STRIDE + c * 2) = f2bf(acc[i][j][k]);
        }
    __syncthreads();
    if (tid < MT) {
      lse_bf_row(smem + tid * EPI_STRIDE, rs[0], rs[1]);
    } else if (rowloc >= 0) {
      const unsigned char* b0 = smem + rowloc * EPI_STRIDE + sub * 64;
#pragma unroll
      for (int c = 0; c < 8; ++c) {
        short4v v = *(const short4v*)(b0 + c * 8);
        TK10(bf2f(v.x)); TK10(bf2f(v.y)); TK10(bf2f(v.z)); TK10(bf2f(v.w));
      }
    }
    __syncthreads();
  }

  // ---- block end: LSE partials out; merge 4 sub-lists per outlier row ----
  if (tid < MT) {
    int grow = mblk * MT + tid;
    float2* lseo = (float2*)(ws + WS_LSE);
    lseo[((size_t)which * B_ + grow) * NSPLIT + split] = make_float2(rs[0], rs[1]);
  }
  if (tid >= 128) {
    float* dst = &tlbuf[(tid - 128) * 10];
#pragma unroll
    for (int i = 0; i < 10; ++i) dst[i] = rs[i];
  }
  __syncthreads();
  if (tid < 32 && tid < noc) {
    float m0 = -1e30f, m1 = -1e30f, m2 = -1e30f, m3 = -1e30f, m4 = -1e30f;
    float m5 = -1e30f, m6 = -1e30f, m7 = -1e30f, m8 = -1e30f, m9 = -1e30f;
#pragma unroll
    for (int s = 0; s < 4; ++s)
#pragma unroll
      for (int i = 0; i < 10; ++i)
        tkins(tlbuf[(tid * 4 + s) * 10 + i], m0, m1, m2, m3, m4, m5, m6, m7, m8, m9);
    int grow = mblk * MT + olist[tid];
    float* dst = (float*)(ws + WS_TOPK) +
                 ((size_t)which * B_ + grow) * NSPLIT * 10 + (size_t)split * 10;
    dst[0] = m0; dst[1] = m1; dst[2] = m2; dst[3] = m3; dst[4] = m4;
    dst[5] = m5; dst[6] = m6; dst[7] = m7; dst[8] = m8; dst[9] = m9;
  }
}

__global__ void finalize_rows(
    const float* __restrict__ p, const float* __restrict__ queue,
    const float* __restrict__ maskp, const int* __restrict__ label,
    char* __restrict__ ws) {
  const int row = blockIdx.x;
  const int l = threadIdx.x >> 6;     // 0: cos1 loss, 1: cos2 loss
  const int lane = threadIdx.x & 63;
  const int lab = label[row];
  float* wsf = (float*)ws;
  int* wsi = (int*)ws;

  if (lab != -1) {
    // ---- merge 128 split (M,Z) partials (2 per lane, then wave reduce) ----
    const float2* lsep = (const float2*)(ws + WS_LSE) + ((size_t)l * B_ + row) * NSPLIT;
    float2 a = lsep[lane];
    float2 b = lsep[lane + 64];
    float M = fmaxf(a.x, b.x);
    float z = a.y * __expf(a.x - M) + b.y * __expf(b.x - M);
    float Mx = M;
#pragma unroll
    for (int o = 1; o < 64; o <<= 1) Mx = fmaxf(Mx, __shfl_xor(Mx, o, 64));
    z *= __expf(M - Mx);
#pragma unroll
    for (int o = 1; o < 64; o <<= 1) z += __shfl_xor(z, o, 64);

    // ---- exact fp32 gt dot(s) ----
    const float* prow = p + (size_t)row * D_;
    const float* q0r = queue + (size_t)lab * D_;
    const float* q1r = queue + ((size_t)Q_ + (size_t)lab) * D_;
    int c = lane * 8;
    float4 a0 = *(const float4*)(prow + c);
    float4 a1 = *(const float4*)(prow + c + 4);
    float4 b0 = *(const float4*)(q0r + c);
    float4 b1 = *(const float4*)(q0r + c + 4);
    float d0 = a0.x * b0.x + a0.y * b0.y + a0.z * b0.z + a0.w * b0.w
             + a1.x * b1.x + a1.y * b1.y + a1.z * b1.z + a1.w * b1.w;
    float d1 = 0.0f;
    if (l == 1) {
      float4 c0 = *(const float4*)(q1r + c);
      float4 c1 = *(const float4*)(q1r + c + 4);
      d1 = a0.x * c0.x + a0.y * c0.y + a0.z * c0.z + a0.w * c0.w
         + a1.x * c1.x + a1.y * c1.y + a1.z * c1.z + a1.w * c1.w;
    }
#pragma unroll
    for (int o = 1; o < 64; o <<= 1) {
      d0 += __shfl_xor(d0, o, 64);
      d1 += __shfl_xor(d1, o, 64);
    }
    float gt;
    if (l == 0) gt = d0;
    else { float m = maskp[lab]; gt = fmaf(m, d1 - d0, d0); }

    if (lane == 0) {
      float t1 = __expf(fmaf(gt, 32.0f, -Mx));
      float t2 = __expf(fmaf(gt - 0.4f, 32.0f, -Mx));
      float Zc = z - t1 + t2;
      float ce = Mx + __logf(Zc) - (gt - 0.4f) * 32.0f;
      atomicAdd(&wsf[0], ce);
      if (l == 0) atomicAdd(&wsi[2], 1);
    }
  } else {
    // ---- merge 128 sorted top-10 lists (2 per lane), then tournament ----
    const float* tp = (const float*)(ws + WS_TOPK) + ((size_t)l * B_ + row) * NSPLIT * 10;
    const float* pa = tp + (size_t)lane * 10;
    const float* pb = tp + (size_t)(lane + 64) * 10;
    float t0 = pa[0], t1 = pa[1], t2 = pa[2], t3 = pa[3], t4 = pa[4];
    float t5 = pa[5], t6 = pa[6], t7 = pa[7], t8 = pa[8], t9 = pa[9];
#pragma unroll
    for (int i = 0; i < 10; ++i)
      tkins(pb[i], t0, t1, t2, t3, t4, t5, t6, t7, t8, t9);
    float ssum = 0.0f;
#pragma unroll
    for (int r10 = 0; r10 < 10; ++r10) {
      float v = t0;
      int idx = lane;
#pragma unroll
      for (int o = 1; o < 64; o <<= 1) {
        float ov = __shfl_xor(v, o, 64);
        int oi = __shfl_xor(idx, o, 64);
        bool take = (ov > v) || (ov == v && oi < idx);
        v = take ? ov : v;
        idx = take ? oi : idx;
      }
      ssum += fmaxf(v, 0.0f);
      if (idx == lane) {
        t0 = t1; t1 = t2; t2 = t3; t3 = t4; t4 = t5;
        t5 = t6; t6 = t7; t7 = t8; t8 = t9; t9 = -1e30f;
      }
    }
    if (lane == 0) {
      atomicAdd(&wsf[1], ssum * 0.1f);
      if (l == 0) atomicAdd(&wsi[3], 1);
    }
  }
}

__global__ void finalize_scalar(const char* __restrict__ ws, float* __restrict__ out) {
  const float* wsf = (const float*)ws;
  const int* wsi = (const int*)ws;
  float loss = 0.0f;
  if (wsi[2] > 0) loss += wsf[0] / (float)wsi[2];
  if (wsi[3] > 0) loss += wsf[1] / (float)wsi[3];
  out[0] = loss;
}

extern "C" void kernel_launch(void* const* d_in, const int* in_sizes, int n_in,
                              void* d_out, int out_size, void* d_ws, size_t ws_size,
                              hipStream_t stream) {
  const float* p     = (const float*)d_in[0];
  const float* queue = (const float*)d_in[1];
  const float* maskp = (const float*)d_in[2];
  const int*   label = (const int*)d_in[3];
  float* out = (float*)d_out;
  char* ws = (char*)d_ws;

  unsigned short* pbf  = (unsigned short*)(ws + WS_PBF);
  unsigned short* qbf0 = (unsigned short*)(ws + WS_QBF0);
  unsigned short* wbf  = (unsigned short*)(ws + WS_WBF);

  hipMemsetAsync(ws, 0, 16, stream);  // zero the atomic accumulators

  // queue fp32 -> {qbf0, wbf}; one wave per row, 4 rows/block
  cvt_queue_kernel<<<Q_ / 4, 256, 0, stream>>>(queue, maskp, qbf0, wbf);
  cvt_bf16_kernel<<<256, 256, 0, stream>>>(p, pbf, (B_ * D_) / 8);

  dim3 g1(NSPLIT, 16);   // x=split -> XCD = split%8; y = mblk*2 + which
  fused_gemm_partial<<<g1, 256, 0, stream>>>(pbf, qbf0, wbf, label, ws);
  finalize_rows<<<B_, 128, 0, stream>>>(p, queue, maskp, label, ws);
  finalize_scalar<<<1, 1, 0, stream>>>(ws, out);
}